// Round 2
// baseline (1201.184 us; speedup 1.0000x reference)
//
#include <hip/hip_runtime.h>
#include <hip/hip_bf16.h>

typedef __attribute__((ext_vector_type(8))) short short8;
typedef __attribute__((ext_vector_type(8))) _Float16 half8;
typedef __attribute__((ext_vector_type(4))) float f32x4;
typedef __attribute__((ext_vector_type(4))) unsigned short ushort4v;
typedef unsigned short us;

#define GLDS16(G, L) __builtin_amdgcn_global_load_lds( \
    (const __attribute__((address_space(1))) void*)(G), \
    (__attribute__((address_space(3))) void*)(L), 16, 0, 0)

__device__ __forceinline__ us f2bf(float x) {
    unsigned int u = __builtin_bit_cast(unsigned int, x);
    u += 0x7fffu + ((u >> 16) & 1u);
    return (us)(u >> 16);
}
__device__ __forceinline__ float bf2f(us h) {
    unsigned int u = ((unsigned int)h) << 16;
    return __builtin_bit_cast(float, u);
}

__global__ void k_sentinel(float* p) {
    if (threadIdx.x == 0 && blockIdx.x == 0) p[0] = 12345.0f;
}

// ---------------- split fp32 -> bf16 hi + bf16 lo ----------------
__global__ void k_split(const float* __restrict__ in, us* __restrict__ hi,
                        us* __restrict__ lo, long n4) {
    long i = (long)blockIdx.x * blockDim.x + threadIdx.x;
    long stride = (long)gridDim.x * blockDim.x;
    for (; i < n4; i += stride) {
        float4 v = ((const float4*)in)[i];
        float vv[4] = {v.x, v.y, v.z, v.w};
        ushort4v h, l;
#pragma unroll
        for (int j = 0; j < 4; j++) {
            us hj = f2bf(vv[j]);
            h[j] = hj;
            l[j] = f2bf(vv[j] - bf2f(hj));
        }
        ((ushort4v*)hi)[i] = h;
        ((ushort4v*)lo)[i] = l;
    }
}

// ---------------- weight transpose+split: f32 [K][N] -> bf16 [N][K] ----------------
template <bool LO>
__global__ void k_wtrans(const float* __restrict__ in, us* __restrict__ hi,
                         us* __restrict__ lo, int K, int N) {
    __shared__ float tile[32][33];
    int n0 = blockIdx.x * 32, k0 = blockIdx.y * 32;
    int tx = threadIdx.x, ty = threadIdx.y;
#pragma unroll
    for (int r = ty; r < 32; r += 8)
        tile[r][tx] = in[(size_t)(k0 + r) * N + n0 + tx];
    __syncthreads();
#pragma unroll
    for (int r = ty; r < 32; r += 8) {
        float x = tile[tx][r];
        size_t o = (size_t)(n0 + r) * K + k0 + tx;
        us h = f2bf(x);
        hi[o] = h;
        if (LO) lo[o] = f2bf(x - bf2f(h));
    }
}

// ---------------- row softmax: 2048 fp32 -> 2048 bf16, one block per row ----------------
__device__ __forceinline__ float wredmax(float v) {
#pragma unroll
    for (int off = 32; off > 0; off >>= 1) v = fmaxf(v, __shfl_xor(v, off, 64));
    return v;
}
__device__ __forceinline__ float wredsum(float v) {
#pragma unroll
    for (int off = 32; off > 0; off >>= 1) v += __shfl_xor(v, off, 64);
    return v;
}

__global__ __launch_bounds__(256) void k_softmax(const float* __restrict__ S,
                                                 us* __restrict__ P) {
    __shared__ float red[8];
    size_t base = (size_t)blockIdx.x * 2048;
    int t = threadIdx.x;
    float4 a = ((const float4*)(S + base))[2 * t];
    float4 b = ((const float4*)(S + base))[2 * t + 1];
    float v[8] = {a.x, a.y, a.z, a.w, b.x, b.y, b.z, b.w};
    float m = v[0];
#pragma unroll
    for (int j = 1; j < 8; j++) m = fmaxf(m, v[j]);
    m = wredmax(m);
    int wv = t >> 6;
    if ((t & 63) == 0) red[wv] = m;
    __syncthreads();
    m = fmaxf(fmaxf(red[0], red[1]), fmaxf(red[2], red[3]));
    float s = 0.f;
#pragma unroll
    for (int j = 0; j < 8; j++) { v[j] = __expf(v[j] - m); s += v[j]; }
    s = wredsum(s);
    if ((t & 63) == 0) red[4 + wv] = s;
    __syncthreads();
    s = red[4] + red[5] + red[6] + red[7];
    float inv = 1.f / s;
    ushort4v o0, o1;
#pragma unroll
    for (int j = 0; j < 4; j++) o0[j] = f2bf(v[j] * inv);
#pragma unroll
    for (int j = 0; j < 4; j++) o1[j] = f2bf(v[4 + j] * inv);
    ((ushort4v*)(P + base))[2 * t] = o0;
    ((ushort4v*)(P + base))[2 * t + 1] = o1;
}

// ---------------- GEMM: C[M][N] = act(A[M][K] * B[N][K]^T + bias) ----------------
// NPASS=3: A,B given as hi/lo bf16 pairs, acc = ah*bh + ah*bl + al*bh
// OUT_MODE: 0=f32  1=bf16  2=bf16 split (hi->C0, lo->C1)
//           3=bf16 transposed per 2048-row batch: C0[(row>>11)*N*2048 + col*2048 + (row&2047)]
//           4=fp16
// F16IN: A,B buffers hold fp16 bit patterns (NPASS must be 1)
template <int NPASS, int OUT_MODE, bool GELU_ACT, bool F16IN>
__global__ __launch_bounds__(256, 2) void k_gemm(
    const us* __restrict__ Ahi, const us* __restrict__ Alo,
    const us* __restrict__ Bhi, const us* __restrict__ Blo,
    const float* __restrict__ bias,
    void* __restrict__ C0, void* __restrict__ C1,
    int M, int N, int K, long sA, long sB, long sC) {
    constexpr int NT = (NPASS == 3) ? 4 : 2;
    __shared__ __align__(16) us lds[NT][4096];  // tiles: 0=Ahi 1=Bhi 2=Alo 3=Blo

    const int tid = threadIdx.x;
    const int wave = tid >> 6, lane = tid & 63;
    const int wr = wave >> 1, wc = wave & 1;
    const int l15 = lane & 15, l4 = lane >> 4;
    const int m0 = blockIdx.x * 128, n0 = blockIdx.y * 128;
    const size_t zA = (size_t)blockIdx.z * sA;
    const size_t zB = (size_t)blockIdx.z * sB;
    const size_t zC = (size_t)blockIdx.z * sC;
    const us* pAh = Ahi + zA;
    const us* pBh = Bhi + zB;
    const us* pAl = (NPASS == 3) ? (Alo + zA) : nullptr;
    const us* pBl = (NPASS == 3) ? (Blo + zB) : nullptr;

    f32x4 acc[4][4] = {};

    // stage 128x32 tile; LDS dest linear, XOR-swizzle applied on the GLOBAL source
    // (rule #21). chunk ^= (row>>1)&3 -> fragment ds_read_b128 is 2-way (free).
    auto stage = [&](const us* __restrict__ g, us* l, int r0, int kk) {
#pragma unroll
        for (int i = 0; i < 2; i++) {
            int s = (i << 8) + tid;  // slot 0..511, 16B each
            int row = s >> 2;
            int csw = s & 3;
            int chunk = csw ^ ((row >> 1) & 3);
            const us* src = g + (size_t)(r0 + row) * K + kk + chunk * 8;
            us* dst = l + (((i << 8) + (wave << 6)) << 3);  // wave-uniform base
            GLDS16(src, dst);
        }
    };

    for (int kk = 0; kk < K; kk += 32) {
        stage(pAh, lds[0], m0, kk);
        stage(pBh, lds[1], n0, kk);
        if (NPASS == 3) {
            stage(pAl, lds[2], m0, kk);
            stage(pBl, lds[3], n0, kk);
        }
        __syncthreads();  // compiler drains vmcnt before s_barrier

        short8 ah[4], bh[4], al[4], bl[4];
#pragma unroll
        for (int f = 0; f < 4; f++) {
            int ra = (wr << 6) + (f << 4) + l15;
            ah[f] = *(const short8*)(&lds[0][(ra << 5) + ((l4 ^ ((ra >> 1) & 3)) << 3)]);
            int rb = (wc << 6) + (f << 4) + l15;
            bh[f] = *(const short8*)(&lds[1][(rb << 5) + ((l4 ^ ((rb >> 1) & 3)) << 3)]);
            if (NPASS == 3) {
                al[f] = *(const short8*)(&lds[2][(ra << 5) + ((l4 ^ ((ra >> 1) & 3)) << 3)]);
                bl[f] = *(const short8*)(&lds[3][(rb << 5) + ((l4 ^ ((rb >> 1) & 3)) << 3)]);
            }
        }
#pragma unroll
        for (int fm = 0; fm < 4; fm++)
#pragma unroll
            for (int fn = 0; fn < 4; fn++) {
                if (F16IN) {
                    acc[fm][fn] = __builtin_amdgcn_mfma_f32_16x16x32_f16(
                        __builtin_bit_cast(half8, ah[fm]), __builtin_bit_cast(half8, bh[fn]),
                        acc[fm][fn], 0, 0, 0);
                } else {
                    acc[fm][fn] = __builtin_amdgcn_mfma_f32_16x16x32_bf16(ah[fm], bh[fn], acc[fm][fn], 0, 0, 0);
                    if (NPASS == 3) {
                        acc[fm][fn] = __builtin_amdgcn_mfma_f32_16x16x32_bf16(ah[fm], bl[fn], acc[fm][fn], 0, 0, 0);
                        acc[fm][fn] = __builtin_amdgcn_mfma_f32_16x16x32_bf16(al[fm], bh[fn], acc[fm][fn], 0, 0, 0);
                    }
                }
            }
        __syncthreads();
    }

    // epilogue: C/D layout col=lane&15, row=(lane>>4)*4+reg [m89-verified]
    float bv[4];
#pragma unroll
    for (int fn = 0; fn < 4; fn++)
        bv[fn] = bias ? bias[n0 + (wc << 6) + (fn << 4) + l15] : 0.f;

#pragma unroll
    for (int fm = 0; fm < 4; fm++) {
        int rbase = m0 + (wr << 6) + (fm << 4) + (l4 << 2);
#pragma unroll
        for (int fn = 0; fn < 4; fn++) {
            int col = n0 + (wc << 6) + (fn << 4) + l15;
#pragma unroll
            for (int r = 0; r < 4; r++) {
                float x = acc[fm][fn][r] + bv[fn];
                if (GELU_ACT) x = 0.5f * x * (1.f + erff(x * 0.70710678118654752f));
                size_t row = (size_t)(rbase + r);
                if (OUT_MODE == 3) {
                    size_t o = ((row >> 11) * (size_t)N + (size_t)col) * 2048 + (row & 2047);
                    ((us*)C0)[o] = f2bf(x);
                } else {
                    size_t o = zC + row * N + col;
                    if (OUT_MODE == 0) {
                        ((float*)C0)[o] = x;
                    } else if (OUT_MODE == 1) {
                        ((us*)C0)[o] = f2bf(x);
                    } else if (OUT_MODE == 2) {
                        us h = f2bf(x);
                        ((us*)C0)[o] = h;
                        ((us*)C1)[o] = f2bf(x - bf2f(h));
                    } else if (OUT_MODE == 4) {
                        ((_Float16*)C0)[o] = (_Float16)x;
                    }
                }
            }
        }
    }
    (void)M;
}

extern "C" void kernel_launch(void* const* d_in, const int* in_sizes, int n_in,
                              void* d_out, int out_size, void* d_ws, size_t ws_size,
                              hipStream_t stream) {
    (void)in_sizes; (void)n_in; (void)out_size;
    const float* g_q   = (const float*)d_in[0];
    const float* g_kv  = (const float*)d_in[1];
    const float* g_Wkv = (const float*)d_in[2];
    const float* g_bkv = (const float*)d_in[3];
    const float* g_Wq  = (const float*)d_in[4];
    const float* g_bq  = (const float*)d_in[5];
    const float* g_W1  = (const float*)d_in[6];
    const float* g_b1  = (const float*)d_in[7];
    const float* g_W2  = (const float*)d_in[8];
    const float* g_b2  = (const float*)d_in[9];

    const size_t R = 33554432ull;     // 32 MiB: one [16384][1024] bf16 activation
    const size_t NHt = 16777216ull;   // elements of such an activation
    const size_t WREG = 16777216ull;  // weight region bytes
    const long SH = 2048L * 1024;     // per-batch activation elements
    const long SS = 2048L * 2048;     // per-batch score elements
    char* ws = (char*)d_ws;
    dim3 tb32(32, 8);

    const size_t need_A = 5 * R + WREG;  // 176 MiB
    const size_t need_B = 4 * R + WREG;  // 144 MiB
    const size_t need_C = 3 * R + WREG;  // 112 MiB

    if (ws_size >= need_A) {
        // ---- Plan A: 2-batch chunks, scores/P/q-frag in d_out ----
        us* qsh = (us*)ws;
        us* khi = (us*)(ws + R);
        us* klo = (us*)(ws + 2 * R);
        us* vT  = (us*)(ws + 3 * R);
        us* qsl = (us*)(ws + 4 * R);
        char* wreg = ws + 5 * R;
        us* wkvThi = (us*)wreg;
        us* wkvTlo = (us*)(wreg + 4194304);
        us* wqThi  = (us*)(wreg + 8388608);
        us* wqTlo  = (us*)(wreg + 10485760);
        us* w1T    = (us*)wreg;             // overlays wkvT (dead by MLP)
        us* w2T    = (us*)(wreg + 8388608); // overlays wqT  (dead by MLP)
        us* cvh = (us*)d_out;
        us* cvl = cvh + NHt;
        float* scores_c = (float*)d_out;                  // 32 MiB
        us* P_c  = (us*)((char*)d_out + 33554432);        // 16 MiB
        us* qh_c = (us*)((char*)d_out + 50331648);        // 8 MiB
        us* ql_c = (us*)((char*)d_out + 58720256);        // 8 MiB

        k_wtrans<true><<<dim3(64, 32), tb32, 0, stream>>>(g_Wkv, wkvThi, wkvTlo, 1024, 2048);
        k_wtrans<true><<<dim3(32, 32), tb32, 0, stream>>>(g_Wq, wqThi, wqTlo, 1024, 1024);
        k_split<<<4096, 256, 0, stream>>>(g_kv, cvh, cvl, 4194304);
        k_gemm<3, 2, false, false><<<dim3(128, 8, 1), 256, 0, stream>>>(
            cvh, cvl, wkvThi, wkvTlo, g_bkv, khi, klo, 16384, 1024, 1024, 0, 0, 0);
        k_gemm<1, 3, false, false><<<dim3(128, 8, 1), 256, 0, stream>>>(
            cvh, nullptr, wkvThi + 1048576, nullptr, g_bkv + 1024, vT, nullptr,
            16384, 1024, 1024, 0, 0, 0);
        k_split<<<4096, 256, 0, stream>>>(g_q, qsh, qsl, 4194304);
        for (int c = 0; c < 4; ++c) {
            size_t ro = (size_t)c * 4096 * 1024;
            k_gemm<3, 2, false, false><<<dim3(32, 8, 1), 256, 0, stream>>>(
                qsh + ro, qsl + ro, wqThi, wqTlo, g_bq, qh_c, ql_c, 4096, 1024, 1024, 0, 0, 0);
            k_gemm<3, 0, false, false><<<dim3(16, 16, 2), 256, 0, stream>>>(
                qh_c, ql_c, khi + ro, klo + ro, nullptr, scores_c, nullptr,
                2048, 2048, 1024, SH, SH, SS);
            k_softmax<<<4096, 256, 0, stream>>>(scores_c, P_c);
            k_gemm<1, 1, false, false><<<dim3(16, 8, 2), 256, 0, stream>>>(
                P_c, nullptr, vT + ro, nullptr, nullptr, qsh + ro, nullptr,
                2048, 1024, 2048, SS, SH, SH);
        }
        k_wtrans<false><<<dim3(128, 32), tb32, 0, stream>>>(g_W1, w1T, nullptr, 1024, 4096);
        k_wtrans<false><<<dim3(32, 128), tb32, 0, stream>>>(g_W2, w2T, nullptr, 4096, 1024);
        us* hidden = khi;  // overlays khi..qsl (134 MiB exact)
        k_gemm<1, 1, true, false><<<dim3(128, 32, 1), 256, 0, stream>>>(
            qsh, nullptr, w1T, nullptr, g_b1, hidden, nullptr, 16384, 4096, 1024, 0, 0, 0);
        k_gemm<1, 0, false, false><<<dim3(128, 8, 1), 256, 0, stream>>>(
            hidden, nullptr, w2T, nullptr, g_b2, d_out, nullptr, 16384, 1024, 4096, 0, 0, 0);
    } else if (ws_size >= need_B) {
        // ---- Plan B: 1-batch chunks, q split stays in d_out ----
        us* khi = (us*)ws;
        us* klo = (us*)(ws + R);
        us* vT  = (us*)(ws + 2 * R);
        char* sc = ws + 3 * R;
        float* scores_c = (float*)sc;
        us* P_c  = (us*)(sc + 16777216);
        us* qh_c = (us*)(sc + 25165824);
        us* ql_c = (us*)(sc + 29360128);
        char* wreg = ws + 4 * R;
        us* wkvThi = (us*)wreg;
        us* wkvTlo = (us*)(wreg + 4194304);
        us* wqThi  = (us*)(wreg + 8388608);
        us* wqTlo  = (us*)(wreg + 10485760);
        us* w1T    = (us*)wreg;
        us* w2T    = (us*)(wreg + 8388608);
        us* cvh = (us*)d_out;
        us* cvl = cvh + NHt;

        k_wtrans<true><<<dim3(64, 32), tb32, 0, stream>>>(g_Wkv, wkvThi, wkvTlo, 1024, 2048);
        k_wtrans<true><<<dim3(32, 32), tb32, 0, stream>>>(g_Wq, wqThi, wqTlo, 1024, 1024);
        k_split<<<4096, 256, 0, stream>>>(g_kv, cvh, cvl, 4194304);
        k_gemm<3, 2, false, false><<<dim3(128, 8, 1), 256, 0, stream>>>(
            cvh, cvl, wkvThi, wkvTlo, g_bkv, khi, klo, 16384, 1024, 1024, 0, 0, 0);
        k_gemm<1, 3, false, false><<<dim3(128, 8, 1), 256, 0, stream>>>(
            cvh, nullptr, wkvThi + 1048576, nullptr, g_bkv + 1024, vT, nullptr,
            16384, 1024, 1024, 0, 0, 0);
        k_split<<<4096, 256, 0, stream>>>(g_q, cvh, cvl, 4194304);
        for (int c = 0; c < 8; ++c) {
            size_t ro = (size_t)c * 2048 * 1024;
            k_gemm<3, 2, false, false><<<dim3(16, 8, 1), 256, 0, stream>>>(
                cvh + ro, cvl + ro, wqThi, wqTlo, g_bq, qh_c, ql_c, 2048, 1024, 1024, 0, 0, 0);
            k_gemm<3, 0, false, false><<<dim3(16, 16, 1), 256, 0, stream>>>(
                qh_c, ql_c, khi + ro, klo + ro, nullptr, scores_c, nullptr,
                2048, 2048, 1024, 0, 0, 0);
            k_softmax<<<2048, 256, 0, stream>>>(scores_c, P_c);
            k_gemm<1, 1, false, false><<<dim3(16, 8, 1), 256, 0, stream>>>(
                P_c, nullptr, vT + ro, nullptr, nullptr, cvh + ro, nullptr,
                2048, 1024, 2048, 0, 0, 0);
        }
        k_wtrans<false><<<dim3(128, 32), tb32, 0, stream>>>(g_W1, w1T, nullptr, 1024, 4096);
        k_wtrans<false><<<dim3(32, 128), tb32, 0, stream>>>(g_W2, w2T, nullptr, 4096, 1024);
        us* hidden = khi;  // overlays khi..sc (134 MiB exact)
        k_gemm<1, 1, true, false><<<dim3(128, 32, 1), 256, 0, stream>>>(
            (us*)d_out, nullptr, w1T, nullptr, g_b1, hidden, nullptr, 16384, 4096, 1024, 0, 0, 0);
        k_gemm<1, 0, false, false><<<dim3(128, 8, 1), 256, 0, stream>>>(
            hidden, nullptr, w2T, nullptr, g_b2, d_out, nullptr, 16384, 1024, 4096, 0, 0, 0);
    } else if (ws_size >= need_C) {
        // ---- Plan C: fp16 q/k single-pass scores (lower precision fallback) ----
        us* khF = (us*)ws;
        us* vT  = (us*)(ws + R);
        char* sc = ws + 2 * R;
        float* scores_c = (float*)sc;
        us* P_c  = (us*)(sc + 16777216);
        us* qF_c = (us*)(sc + 25165824);
        char* wreg = ws + 3 * R;
        us* wkvThi = (us*)wreg;
        us* wkvTlo = (us*)(wreg + 4194304);
        us* wqThi  = (us*)(wreg + 8388608);
        us* wqTlo  = (us*)(wreg + 10485760);
        us* w1T    = (us*)wreg;
        us* w2T    = (us*)(wreg + 8388608);
        us* cvh = (us*)d_out;
        us* cvl = cvh + NHt;

        k_wtrans<true><<<dim3(64, 32), tb32, 0, stream>>>(g_Wkv, wkvThi, wkvTlo, 1024, 2048);
        k_wtrans<true><<<dim3(32, 32), tb32, 0, stream>>>(g_Wq, wqThi, wqTlo, 1024, 1024);
        k_split<<<4096, 256, 0, stream>>>(g_kv, cvh, cvl, 4194304);
        k_gemm<3, 4, false, false><<<dim3(128, 8, 1), 256, 0, stream>>>(
            cvh, cvl, wkvThi, wkvTlo, g_bkv, khF, nullptr, 16384, 1024, 1024, 0, 0, 0);
        k_gemm<1, 3, false, false><<<dim3(128, 8, 1), 256, 0, stream>>>(
            cvh, nullptr, wkvThi + 1048576, nullptr, g_bkv + 1024, vT, nullptr,
            16384, 1024, 1024, 0, 0, 0);
        k_split<<<4096, 256, 0, stream>>>(g_q, cvh, cvl, 4194304);
        for (int c = 0; c < 8; ++c) {
            size_t ro = (size_t)c * 2048 * 1024;
            k_gemm<3, 4, false, false><<<dim3(16, 8, 1), 256, 0, stream>>>(
                cvh + ro, cvl + ro, wqThi, wqTlo, g_bq, qF_c, nullptr, 2048, 1024, 1024, 0, 0, 0);
            k_gemm<1, 0, false, true><<<dim3(16, 16, 1), 256, 0, stream>>>(
                qF_c, nullptr, khF + ro, nullptr, nullptr, scores_c, nullptr,
                2048, 2048, 1024, 0, 0, 0);
            k_softmax<<<2048, 256, 0, stream>>>(scores_c, P_c);
            k_gemm<1, 1, false, false><<<dim3(16, 8, 1), 256, 0, stream>>>(
                P_c, nullptr, vT + ro, nullptr, nullptr, cvh + ro, nullptr,
                2048, 1024, 2048, 0, 0, 0);
        }
        k_wtrans<false><<<dim3(128, 32), tb32, 0, stream>>>(g_W1, w1T, nullptr, 1024, 4096);
        k_wtrans<false><<<dim3(32, 128), tb32, 0, stream>>>(g_W2, w2T, nullptr, 4096, 1024);
        // MLP in two row-halves, descending so d_out writes never clobber unread attnout
        for (int h = 1; h >= 0; --h) {
            us* hidden_c = khF;  // overlays khF..sc (dead after attention)
            k_gemm<1, 1, true, false><<<dim3(64, 32, 1), 256, 0, stream>>>(
                (us*)d_out + (size_t)h * 8192 * 1024, nullptr, w1T, nullptr, g_b1,
                hidden_c, nullptr, 8192, 4096, 1024, 0, 0, 0);
            k_gemm<1, 0, false, false><<<dim3(64, 8, 1), 256, 0, stream>>>(
                hidden_c, nullptr, w2T, nullptr, g_b2,
                (float*)d_out + (size_t)h * 8192 * 1024, nullptr, 8192, 1024, 4096, 0, 0, 0);
        }
    } else {
        // ws too small for any plan: plant an unambiguous sentinel (absmax ~12345)
        k_sentinel<<<1, 64, 0, stream>>>((float*)d_out);
    }
}